// Round 1
// baseline (145.222 us; speedup 1.0000x reference)
//
#include <hip/hip_runtime.h>

#define NB 8
#define LL 256
#define DD 256

// ---------------------------------------------------------------------------
// Kernel 1: A = Q Wa^T, Bm = Q Wb^T, Hj = Q Wd^T  (all [B*L, D] fp32 into ws)
// grid (M/64=32, N/64=4, 3), block 256 (16x16), 4x4 per thread, K-chunks of 32
// ---------------------------------------------------------------------------
__global__ __launch_bounds__(256) void gemm3_kernel(
    const float* __restrict__ Q, const float* __restrict__ Wa,
    const float* __restrict__ Wb, const float* __restrict__ Wd,
    float* __restrict__ ws) {
  const int mt = blockIdx.x;
  const int nt = blockIdx.y;
  const int wsel = blockIdx.z;
  const float* __restrict__ W = (wsel == 0) ? Wa : (wsel == 1) ? Wb : Wd;
  float* __restrict__ Out = ws + (size_t)wsel * (NB * LL * DD);

  __shared__ float Qs[32][68];  // [k][m], transposed for float4 reads along m
  __shared__ float Wsh[32][68]; // [k][n]

  const int tid = threadIdx.x;
  const int tx = tid & 15;
  const int ty = tid >> 4;
  const int m0 = mt * 64, n0 = nt * 64;

  const int r = tid >> 3;        // 0..31 (row within half-tile)
  const int kq = (tid & 7) * 4;  // k-quad

  float acc[4][4] = {};

  for (int k0 = 0; k0 < DD; k0 += 32) {
#pragma unroll
    for (int half = 0; half < 2; ++half) {
      float4 q4 = *(const float4*)&Q[(size_t)(m0 + half * 32 + r) * DD + k0 + kq];
      Qs[kq + 0][half * 32 + r] = q4.x;
      Qs[kq + 1][half * 32 + r] = q4.y;
      Qs[kq + 2][half * 32 + r] = q4.z;
      Qs[kq + 3][half * 32 + r] = q4.w;
      float4 w4 = *(const float4*)&W[(size_t)(n0 + half * 32 + r) * DD + k0 + kq];
      Wsh[kq + 0][half * 32 + r] = w4.x;
      Wsh[kq + 1][half * 32 + r] = w4.y;
      Wsh[kq + 2][half * 32 + r] = w4.z;
      Wsh[kq + 3][half * 32 + r] = w4.w;
    }
    __syncthreads();
#pragma unroll 8
    for (int kk = 0; kk < 32; ++kk) {
      float a[4], bv[4];
      *(float4*)a = *(const float4*)&Qs[kk][ty * 4];
      *(float4*)bv = *(const float4*)&Wsh[kk][tx * 4];
#pragma unroll
      for (int ii = 0; ii < 4; ++ii)
#pragma unroll
        for (int jj = 0; jj < 4; ++jj)
          acc[ii][jj] = fmaf(a[ii], bv[jj], acc[ii][jj]);
    }
    __syncthreads();
  }
#pragma unroll
  for (int ii = 0; ii < 4; ++ii) {
    float4 o = make_float4(acc[ii][0], acc[ii][1], acc[ii][2], acc[ii][3]);
    *(float4*)&Out[(size_t)(m0 + ty * 4 + ii) * DD + n0 + tx * 4] = o;
  }
}

// ---------------------------------------------------------------------------
// Kernel 2: fused edge-score + masked softmax + aggregation + residual relu.
// One block per (b, 8-row i-tile): grid 256, block 256.
// ---------------------------------------------------------------------------
__global__ __launch_bounds__(256) void fused_kernel(
    const float* __restrict__ Q, const int* __restrict__ sdep,
    const float* __restrict__ w2, const float* __restrict__ ws,
    float* __restrict__ out) {
  const int b = blockIdx.x >> 5;
  const int it = blockIdx.x & 31;
  const int i0 = it * 8;
  const float* __restrict__ Ag = ws;
  const float* __restrict__ Bg = ws + (size_t)NB * LL * DD;
  const float* __restrict__ Hg = ws + (size_t)2 * NB * LL * DD;

  __shared__ float As[8][260];   // A rows for this i-tile (also reused for agg)
  __shared__ float w2s[256];
  __shared__ float Bs[32][260];  // Bm / Hj tile staging
  __shared__ float Ts[8][264];   // t, then softmax weights w

  const int tid = threadIdx.x;
  const int li = tid & 7;    // i within tile
  const int g8 = tid >> 3;   // 0..31 : jj in phase B, c-quad in phase D

  // ---- Phase A: stage A rows + w2 ----
#pragma unroll
  for (int p = 0; p < 2; ++p) {
    int idx = tid + p * 256;  // 0..511 float4s (8 rows x 64)
    int rr = idx >> 6, c4 = (idx & 63) * 4;
    float4 v = *(const float4*)&Ag[(size_t)(b * LL + i0 + rr) * DD + c4];
    As[rr][c4 + 0] = v.x; As[rr][c4 + 1] = v.y;
    As[rr][c4 + 2] = v.z; As[rr][c4 + 3] = v.w;
  }
  if (tid < 64) {
    float4 v = *(const float4*)&w2[tid * 4];
    w2s[tid * 4 + 0] = v.x; w2s[tid * 4 + 1] = v.y;
    w2s[tid * 4 + 2] = v.z; w2s[tid * 4 + 3] = v.w;
  }
  __syncthreads();

  // ---- Phase B: t[i][j] = sum_c w2_c * relu(A_ic + B_jc), j-tiles of 32 ----
  for (int jt = 0; jt < 8; ++jt) {
#pragma unroll
    for (int p = 0; p < 8; ++p) {
      int idx = tid + p * 256;  // 32 rows x 64 float4
      int rr = idx >> 6, c4 = (idx & 63) * 4;
      float4 v = *(const float4*)&Bg[(size_t)(b * LL + jt * 32 + rr) * DD + c4];
      Bs[rr][c4 + 0] = v.x; Bs[rr][c4 + 1] = v.y;
      Bs[rr][c4 + 2] = v.z; Bs[rr][c4 + 3] = v.w;
    }
    __syncthreads();
    float acc4[4] = {0.f, 0.f, 0.f, 0.f};
#pragma unroll 8
    for (int c4 = 0; c4 < 64; ++c4) {
      float a[4], bv[4], w[4];
      *(float4*)a = *(const float4*)&As[li][c4 * 4];
      *(float4*)bv = *(const float4*)&Bs[g8][c4 * 4];
      *(float4*)w = *(const float4*)&w2s[c4 * 4];
#pragma unroll
      for (int u = 0; u < 4; ++u) {
        float s = fmaxf(a[u] + bv[u], 0.f);
        acc4[u] = fmaf(w[u], s, acc4[u]);
      }
    }
    Ts[li][jt * 32 + g8] = (acc4[0] + acc4[1]) + (acc4[2] + acc4[3]);
    __syncthreads();
  }

  // ---- Phase C: masked softmax over j (32 lanes per row) ----
  {
    const int i = tid >> 5;  // 0..7
    const int l = tid & 31;
    const int* __restrict__ srow = &sdep[(size_t)(b * LL + i0 + i) * LL];
    float vals[8];
    float m = -3.0e38f;
#pragma unroll
    for (int k = 0; k < 8; ++k) {
      int j = l + 32 * k;
      bool e = srow[j] > 0;
      vals[k] = e ? Ts[i][j] : -3.0e38f;
      m = fmaxf(m, vals[k]);
    }
#pragma unroll
    for (int off = 16; off >= 1; off >>= 1) m = fmaxf(m, __shfl_xor(m, off));
    float s = 0.f;
#pragma unroll
    for (int k = 0; k < 8; ++k) {
      float e = (vals[k] > -1.0e30f) ? __expf(vals[k] - m) : 0.f;
      vals[k] = e;
      s += e;
    }
#pragma unroll
    for (int off = 16; off >= 1; off >>= 1) s += __shfl_xor(s, off);
    float inv = (s > 0.f) ? 1.0f / s : 0.f;
#pragma unroll
    for (int k = 0; k < 8; ++k) Ts[i][l + 32 * k] = vals[k] * inv;
  }
  __syncthreads();

  // ---- Phase D: agg[i][c] = sum_j w[i][j] * Hj[j][c] ----
  float a0[4] = {0.f, 0.f, 0.f, 0.f};
  float a1[4] = {0.f, 0.f, 0.f, 0.f};
  for (int jt = 0; jt < 8; ++jt) {
#pragma unroll
    for (int p = 0; p < 8; ++p) {
      int idx = tid + p * 256;
      int rr = idx >> 6, c4 = (idx & 63) * 4;
      float4 v = *(const float4*)&Hg[(size_t)(b * LL + jt * 32 + rr) * DD + c4];
      Bs[rr][c4 + 0] = v.x; Bs[rr][c4 + 1] = v.y;
      Bs[rr][c4 + 2] = v.z; Bs[rr][c4 + 3] = v.w;
    }
    __syncthreads();
    float tw[32];
#pragma unroll
    for (int q = 0; q < 8; ++q)
      *(float4*)&tw[q * 4] = *(const float4*)&Ts[li][jt * 32 + q * 4];
#pragma unroll 8
    for (int j = 0; j < 32; ++j) {
      float wgt = tw[j];
      float h0[4], h1[4];
      *(float4*)h0 = *(const float4*)&Bs[j][g8 * 4];
      *(float4*)h1 = *(const float4*)&Bs[j][128 + g8 * 4];
#pragma unroll
      for (int u = 0; u < 4; ++u) {
        a0[u] = fmaf(wgt, h0[u], a0[u]);
        a1[u] = fmaf(wgt, h1[u], a1[u]);
      }
    }
    __syncthreads();
  }

  // ---- Phase E: out = relu(Q + agg) ----
  *(float4*)&As[li][g8 * 4] = *(float4*)a0;
  *(float4*)&As[li][128 + g8 * 4] = *(float4*)a1;
  __syncthreads();
#pragma unroll
  for (int p = 0; p < 2; ++p) {
    int idx = tid + p * 256;
    int rr = idx >> 6, c4 = (idx & 63) * 4;
    float4 q4 = *(const float4*)&Q[(size_t)(b * LL + i0 + rr) * DD + c4];
    float4 av = *(const float4*)&As[rr][c4];
    float4 o;
    o.x = fmaxf(q4.x + av.x, 0.f);
    o.y = fmaxf(q4.y + av.y, 0.f);
    o.z = fmaxf(q4.z + av.z, 0.f);
    o.w = fmaxf(q4.w + av.w, 0.f);
    *(float4*)&out[(size_t)(b * LL + i0 + rr) * DD + c4] = o;
  }
}

// ---------------------------------------------------------------------------
// Kernel 3: tail outputs (wordlens, syntactic_dep) converted int -> float,
// since the harness reads the whole concatenated d_out as float32.
// ---------------------------------------------------------------------------
__global__ __launch_bounds__(256) void tail_kernel(
    const int* __restrict__ wl, const int* __restrict__ sdep,
    float* __restrict__ out) {
  int idx = blockIdx.x * 256 + threadIdx.x;
  const int total = 8 + NB * LL * LL;
  if (idx >= total) return;
  float* dst = out + (size_t)NB * LL * DD;
  dst[idx] = (idx < 8) ? (float)wl[idx] : (float)sdep[idx - 8];
}

extern "C" void kernel_launch(void* const* d_in, const int* in_sizes, int n_in,
                              void* d_out, int out_size, void* d_ws, size_t ws_size,
                              hipStream_t stream) {
  const float* Q    = (const float*)d_in[0];
  const int*   wl   = (const int*)d_in[1];
  const int*   sdep = (const int*)d_in[2];
  const float* Wa   = (const float*)d_in[3];
  const float* Wb   = (const float*)d_in[4];
  const float* w2   = (const float*)d_in[5];
  const float* Wd   = (const float*)d_in[6];
  float* out = (float*)d_out;
  float* ws  = (float*)d_ws;  // needs 3 * 2MB = 6MB

  gemm3_kernel<<<dim3(32, 4, 3), 256, 0, stream>>>(Q, Wa, Wb, Wd, ws);
  tail_kernel<<<2049, 256, 0, stream>>>(wl, sdep, out);
  fused_kernel<<<256, 256, 0, stream>>>(Q, sdep, w2, ws, out);
}

// Round 2
// 128.365 us; speedup vs baseline: 1.1313x; 1.1313x over previous
//
#include <hip/hip_runtime.h>

#define NB 8
#define LL 256
#define DD 256

// ---------------------------------------------------------------------------
// Kernel 1: A = Q Wa^T, Bm = Q Wb^T, Hj = Q Wd^T  (all [B*L, D] fp32 into ws)
// 32x64 tiles -> grid (64,4,3) = 768 blocks (3 blocks/CU, 12 waves/CU).
// Per thread 2x4 acc, K-chunks of 32.
// ---------------------------------------------------------------------------
__global__ __launch_bounds__(256) void gemm3_kernel(
    const float* __restrict__ Q, const float* __restrict__ Wa,
    const float* __restrict__ Wb, const float* __restrict__ Wd,
    float* __restrict__ ws) {
  const int mt = blockIdx.x;   // 64 m-tiles of 32
  const int nt = blockIdx.y;   // 4 n-tiles of 64
  const int wsel = blockIdx.z;
  const float* __restrict__ W = (wsel == 0) ? Wa : (wsel == 1) ? Wb : Wd;
  float* __restrict__ Out = ws + (size_t)wsel * (NB * LL * DD);

  __shared__ float Qs[32][34];   // [k][m]
  __shared__ float Wsh[32][66];  // [k][n]

  const int tid = threadIdx.x;
  const int tx = tid & 15;   // n quad
  const int ty = tid >> 4;   // m pair
  const int m0 = mt * 32, n0 = nt * 64;

  float acc[2][4] = {};

  for (int k0 = 0; k0 < DD; k0 += 32) {
    {  // stage Q tile 32m x 32k (1 float4/thread), transposed
      int r = tid >> 3;              // m row 0..31
      int kq = (tid & 7) * 4;        // k quad
      float4 q4 = *(const float4*)&Q[(size_t)(m0 + r) * DD + k0 + kq];
      Qs[kq + 0][r] = q4.x; Qs[kq + 1][r] = q4.y;
      Qs[kq + 2][r] = q4.z; Qs[kq + 3][r] = q4.w;
    }
#pragma unroll
    for (int p = 0; p < 2; ++p) {  // stage W tile 64n x 32k (2 float4/thread)
      int idx = tid + p * 256;
      int r = idx >> 3;              // n row 0..63
      int kq = (idx & 7) * 4;
      float4 w4 = *(const float4*)&W[(size_t)(n0 + r) * DD + k0 + kq];
      Wsh[kq + 0][r] = w4.x; Wsh[kq + 1][r] = w4.y;
      Wsh[kq + 2][r] = w4.z; Wsh[kq + 3][r] = w4.w;
    }
    __syncthreads();
#pragma unroll 8
    for (int kk = 0; kk < 32; ++kk) {
      float a[2], bv[4];
      *(float2*)a = *(const float2*)&Qs[kk][ty * 2];
      *(float4*)bv = *(const float4*)&Wsh[kk][tx * 4];
#pragma unroll
      for (int ii = 0; ii < 2; ++ii)
#pragma unroll
        for (int jj = 0; jj < 4; ++jj)
          acc[ii][jj] = fmaf(a[ii], bv[jj], acc[ii][jj]);
    }
    __syncthreads();
  }
#pragma unroll
  for (int ii = 0; ii < 2; ++ii) {
    float4 o = make_float4(acc[ii][0], acc[ii][1], acc[ii][2], acc[ii][3]);
    *(float4*)&Out[(size_t)(m0 + ty * 2 + ii) * DD + n0 + tx * 4] = o;
  }
}

// ---------------------------------------------------------------------------
// Kernel 2: edge scores t[b,i,j] = sum_c w2_c * relu(A_ic + B_jc), pre-masked.
// 32i x 32j tile per block, grid (8 jt, 8 it, 8 b) = 512 blocks, 2x2/thread.
// A/B tiles XOR-swizzled (rows are 1KB apart -> col-quad ^ (row&7)).
// ---------------------------------------------------------------------------
__global__ __launch_bounds__(256) void edge_kernel(
    const int* __restrict__ sdep, const float* __restrict__ w2,
    const float* __restrict__ ws, float* __restrict__ T) {
  const int jt = blockIdx.x, it = blockIdx.y, b = blockIdx.z;
  const int i0 = it * 32, j0 = jt * 32;
  const float* __restrict__ Ag = ws;
  const float* __restrict__ Bg = ws + (size_t)NB * LL * DD;

  __shared__ float As[32][256];
  __shared__ float Bs[32][256];
  __shared__ float w2s[256];

  const int tid = threadIdx.x;
#pragma unroll
  for (int p = 0; p < 8; ++p) {
    int idx = tid + p * 256;
    int r = idx >> 6, c4 = idx & 63;
    int cs = (c4 ^ (r & 7)) * 4;
    float4 va = *(const float4*)&Ag[(size_t)(b * LL + i0 + r) * DD + c4 * 4];
    *(float4*)&As[r][cs] = va;
    float4 vb = *(const float4*)&Bg[(size_t)(b * LL + j0 + r) * DD + c4 * 4];
    *(float4*)&Bs[r][cs] = vb;
  }
  if (tid < 64) *(float4*)&w2s[tid * 4] = *(const float4*)&w2[tid * 4];
  __syncthreads();

  const int tx = tid & 15, ty = tid >> 4;
  const int ka = ty & 7, kb = tx & 7;
  float acc00 = 0.f, acc01 = 0.f, acc10 = 0.f, acc11 = 0.f;

#pragma unroll 4
  for (int c4 = 0; c4 < 64; ++c4) {
    float a0[4], a1[4], b0[4], b1[4], w[4];
    int ca = (c4 ^ ka) << 2;
    int cb = (c4 ^ kb) << 2;
    *(float4*)a0 = *(const float4*)&As[ty][ca];
    *(float4*)a1 = *(const float4*)&As[ty + 16][ca];
    *(float4*)b0 = *(const float4*)&Bs[tx][cb];
    *(float4*)b1 = *(const float4*)&Bs[tx + 16][cb];
    *(float4*)w = *(const float4*)&w2s[c4 << 2];
#pragma unroll
    for (int u = 0; u < 4; ++u) {
      acc00 = fmaf(w[u], fmaxf(a0[u] + b0[u], 0.f), acc00);
      acc01 = fmaf(w[u], fmaxf(a0[u] + b1[u], 0.f), acc01);
      acc10 = fmaf(w[u], fmaxf(a1[u] + b0[u], 0.f), acc10);
      acc11 = fmaf(w[u], fmaxf(a1[u] + b1[u], 0.f), acc11);
    }
  }

  const float NEG = -3.0e38f;
  float accs[2][2] = {{acc00, acc01}, {acc10, acc11}};
#pragma unroll
  for (int di = 0; di < 2; ++di)
#pragma unroll
    for (int dj = 0; dj < 2; ++dj) {
      int i = i0 + ty + 16 * di, j = j0 + tx + 16 * dj;
      size_t off = (size_t)(b * LL + i) * LL + j;
      T[off] = (sdep[off] > 0) ? accs[di][dj] : NEG;
    }
}

// ---------------------------------------------------------------------------
// Kernel 3: in-place masked softmax over j. One wave per row, 4 rows/block.
// ---------------------------------------------------------------------------
__global__ __launch_bounds__(256) void softmax_kernel(float* __restrict__ T) {
  const int row = blockIdx.x * 4 + (threadIdx.x >> 6);
  const int l = threadIdx.x & 63;
  float* __restrict__ tr = T + (size_t)row * LL;
  float v[4];
  float m = -3.0e38f;
#pragma unroll
  for (int k = 0; k < 4; ++k) {
    v[k] = tr[l + 64 * k];
    m = fmaxf(m, v[k]);
  }
#pragma unroll
  for (int off = 32; off >= 1; off >>= 1) m = fmaxf(m, __shfl_xor(m, off));
  float s = 0.f;
#pragma unroll
  for (int k = 0; k < 4; ++k) {
    float e = (v[k] > -1.0e30f) ? __expf(v[k] - m) : 0.f;
    v[k] = e;
    s += e;
  }
#pragma unroll
  for (int off = 32; off >= 1; off >>= 1) s += __shfl_xor(s, off);
  float inv = (s > 0.f) ? 1.0f / s : 0.f;
#pragma unroll
  for (int k = 0; k < 4; ++k) tr[l + 64 * k] = v[k] * inv;
}

// ---------------------------------------------------------------------------
// Kernel 4: agg[b,i,c] = sum_j w[b,i,j] * Hj[b,j,c]; out = relu(Q + agg).
// 64i x 32c tile, grid (8 ct, 4 it, 8 b) = 256 blocks, 4i x 2c per thread.
// ---------------------------------------------------------------------------
__global__ __launch_bounds__(256) void agg_kernel(
    const float* __restrict__ Q, const float* __restrict__ Wm,
    const float* __restrict__ ws, float* __restrict__ out) {
  const int ct = blockIdx.x;   // 8 c-tiles of 32
  const int it = blockIdx.y;   // 4 i-tiles of 64
  const int b = blockIdx.z;
  const float* __restrict__ Hg = ws + (size_t)2 * NB * LL * DD;

  __shared__ float Wt[32][66];  // transposed weight chunk: [j][i]
  __shared__ float Hs[32][34];  // [j][c]

  const int tid = threadIdx.x;
  const int tx = tid & 15;   // c pair
  const int ty = tid >> 4;   // i quad
  const int i0 = it * 64, c0 = ct * 32;

  float acc[4][2] = {};

  for (int jc = 0; jc < LL; jc += 32) {
#pragma unroll
    for (int p = 0; p < 2; ++p) {  // stage Wm tile 64i x 32j -> transposed
      int idx = tid + p * 256;
      int ri = idx >> 3;            // i row 0..63
      int q = idx & 7;              // j quad
      float4 v = *(const float4*)&Wm[(size_t)(b * LL + i0 + ri) * LL + jc + q * 4];
      Wt[q * 4 + 0][ri] = v.x; Wt[q * 4 + 1][ri] = v.y;
      Wt[q * 4 + 2][ri] = v.z; Wt[q * 4 + 3][ri] = v.w;
    }
    {  // stage H tile 32j x 32c
      int rj = tid >> 3;            // j row 0..31
      int q = tid & 7;              // c quad
      float4 v = *(const float4*)&Hg[(size_t)(b * LL + jc + rj) * DD + c0 + q * 4];
      *(float4*)&Hs[rj][q * 4] = v;
    }
    __syncthreads();
#pragma unroll 8
    for (int kk = 0; kk < 32; ++kk) {
      float a[4];
      *(float4*)a = *(const float4*)&Wt[kk][ty * 4];
      float2 h = *(const float2*)&Hs[kk][tx * 2];
#pragma unroll
      for (int d = 0; d < 4; ++d) {
        acc[d][0] = fmaf(a[d], h.x, acc[d][0]);
        acc[d][1] = fmaf(a[d], h.y, acc[d][1]);
      }
    }
    __syncthreads();
  }

#pragma unroll
  for (int d = 0; d < 4; ++d) {
    int i = i0 + ty * 4 + d;
    int c = c0 + tx * 2;
    size_t off = (size_t)(b * LL + i) * DD + c;
    float2 q2 = *(const float2*)&Q[off];
    float2 o;
    o.x = fmaxf(q2.x + acc[d][0], 0.f);
    o.y = fmaxf(q2.y + acc[d][1], 0.f);
    *(float2*)&out[off] = o;
  }
}

// ---------------------------------------------------------------------------
// Kernel 5: tail outputs (wordlens, syntactic_dep) converted int -> float.
// ---------------------------------------------------------------------------
__global__ __launch_bounds__(256) void tail_kernel(
    const int* __restrict__ wl, const int* __restrict__ sdep,
    float* __restrict__ out) {
  int idx = blockIdx.x * 256 + threadIdx.x;
  const int total = 8 + NB * LL * LL;
  if (idx >= total) return;
  float* dst = out + (size_t)NB * LL * DD;
  dst[idx] = (idx < 8) ? (float)wl[idx] : (float)sdep[idx - 8];
}

extern "C" void kernel_launch(void* const* d_in, const int* in_sizes, int n_in,
                              void* d_out, int out_size, void* d_ws, size_t ws_size,
                              hipStream_t stream) {
  const float* Q    = (const float*)d_in[0];
  const int*   wl   = (const int*)d_in[1];
  const int*   sdep = (const int*)d_in[2];
  const float* Wa   = (const float*)d_in[3];
  const float* Wb   = (const float*)d_in[4];
  const float* w2   = (const float*)d_in[5];
  const float* Wd   = (const float*)d_in[6];
  float* out = (float*)d_out;
  float* ws  = (float*)d_ws;                       // 8 MB used
  float* Tb  = ws + (size_t)3 * NB * LL * DD;      // t / softmax weights (2 MB)

  gemm3_kernel<<<dim3(64, 4, 3), 256, 0, stream>>>(Q, Wa, Wb, Wd, ws);
  edge_kernel<<<dim3(8, 8, 8), 256, 0, stream>>>(sdep, w2, ws, Tb);
  softmax_kernel<<<512, 256, 0, stream>>>(Tb);
  agg_kernel<<<dim3(8, 4, 8), 256, 0, stream>>>(Q, Tb, ws, out);
  tail_kernel<<<2049, 256, 0, stream>>>(wl, sdep, out);
}

// Round 3
// 121.153 us; speedup vs baseline: 1.1987x; 1.0595x over previous
//
#include <hip/hip_runtime.h>

#define NB 8
#define LL 256
#define DD 256

typedef __attribute__((ext_vector_type(8))) short short8v;  // 8 bf16 (4 VGPR)
typedef __attribute__((ext_vector_type(4))) float f32x4;

__device__ __forceinline__ ushort f2bf(float f) {
  uint u = __float_as_uint(f);
  uint r = (u + 0x7FFFu + ((u >> 16) & 1u)) >> 16;  // RNE
  return (ushort)r;
}

// ---------------------------------------------------------------------------
// Kernel 0: prep — convert Q/Wa/Wb/Wd to bf16, and write tail outputs
// (wordlens + syntactic_dep as floats). Fully independent elementwise work.
// ---------------------------------------------------------------------------
__global__ __launch_bounds__(256) void prep_kernel(
    const float* __restrict__ Q, const float* __restrict__ Wa,
    const float* __restrict__ Wb, const float* __restrict__ Wd,
    const int* __restrict__ wl, const int* __restrict__ sdep,
    ushort* __restrict__ Qb, ushort* __restrict__ Wab,
    ushort* __restrict__ Wbb, ushort* __restrict__ Wdb,
    float* __restrict__ tail_out) {
  int g = blockIdx.x * 256 + threadIdx.x;
  if (g < 131072) {                       // Q: 524288 floats = 131072 float4
    float4 v = *(const float4*)&Q[(size_t)g * 4];
    ushort4 pk; pk.x = f2bf(v.x); pk.y = f2bf(v.y); pk.z = f2bf(v.z); pk.w = f2bf(v.w);
    *(ushort4*)&Qb[(size_t)g * 4] = pk;
  } else if (g < 180224) {                // 3 weights x 16384 float4
    int h = g - 131072;
    int wi = h >> 14, o = h & 16383;
    const float* S = (wi == 0) ? Wa : (wi == 1) ? Wb : Wd;
    ushort* D = (wi == 0) ? Wab : (wi == 1) ? Wbb : Wdb;
    float4 v = *(const float4*)&S[(size_t)o * 4];
    ushort4 pk; pk.x = f2bf(v.x); pk.y = f2bf(v.y); pk.z = f2bf(v.z); pk.w = f2bf(v.w);
    *(ushort4*)&D[(size_t)o * 4] = pk;
  } else if (g < 311296) {                // sdep: 131072 int4 -> float4
    int o = g - 180224;
    int4 s = *(const int4*)&sdep[(size_t)o * 4];
    float4 f; f.x = (float)s.x; f.y = (float)s.y; f.z = (float)s.z; f.w = (float)s.w;
    *(float4*)&tail_out[8 + (size_t)o * 4] = f;
  } else if (g == 311296) {               // 8 wordlens
    for (int k = 0; k < 8; ++k) tail_out[k] = (float)wl[k];
  }
}

// ---------------------------------------------------------------------------
// Kernel 1: bf16 MFMA GEMM: z=0: A=Q Wa^T (fp32), z=1: Bm=Q Wb^T (fp32),
// z=2: Hjt[b][c][j] = (Q Wd^T)[b][j][c] in bf16 (transposed for agg B-frag).
// 64x64 tile, 4 waves (2x2 wave grid), mfma_f32_16x16x32_bf16.
// ---------------------------------------------------------------------------
__global__ __launch_bounds__(256) void gemm3_mfma(
    const ushort* __restrict__ Qb, const ushort* __restrict__ Wab,
    const ushort* __restrict__ Wbb, const ushort* __restrict__ Wdb,
    float* __restrict__ A, float* __restrict__ Bm, ushort* __restrict__ Hjt) {
  const int mt = blockIdx.x;  // 32 tiles of 64 rows
  const int nt = blockIdx.y;  // 4 tiles of 64 cols
  const int z = blockIdx.z;
  const ushort* __restrict__ W = (z == 0) ? Wab : (z == 1) ? Wbb : Wdb;

  __shared__ __align__(16) ushort Qs[64][32];
  __shared__ __align__(16) ushort Ws[64][32];

  const int tid = threadIdx.x;
  const int m0 = mt * 64, n0 = nt * 64;
  const int srow = tid >> 2, skc = (tid & 3) * 8;
  const int w = tid >> 6, lane = tid & 63;
  const int wm = w >> 1, wn = w & 1;
  const int fr = lane & 15, fk = (lane >> 4) * 8;

  f32x4 acc[2][2] = {};
  for (int k0 = 0; k0 < DD; k0 += 32) {
    *(uint4*)&Qs[srow][skc] = *(const uint4*)&Qb[(size_t)(m0 + srow) * DD + k0 + skc];
    *(uint4*)&Ws[srow][skc] = *(const uint4*)&W[(size_t)(n0 + srow) * DD + k0 + skc];
    __syncthreads();
    short8v a0 = *(const short8v*)&Qs[wm * 32 + fr][fk];
    short8v a1 = *(const short8v*)&Qs[wm * 32 + 16 + fr][fk];
    short8v b0 = *(const short8v*)&Ws[wn * 32 + fr][fk];
    short8v b1 = *(const short8v*)&Ws[wn * 32 + 16 + fr][fk];
    acc[0][0] = __builtin_amdgcn_mfma_f32_16x16x32_bf16(a0, b0, acc[0][0], 0, 0, 0);
    acc[0][1] = __builtin_amdgcn_mfma_f32_16x16x32_bf16(a0, b1, acc[0][1], 0, 0, 0);
    acc[1][0] = __builtin_amdgcn_mfma_f32_16x16x32_bf16(a1, b0, acc[1][0], 0, 0, 0);
    acc[1][1] = __builtin_amdgcn_mfma_f32_16x16x32_bf16(a1, b1, acc[1][1], 0, 0, 0);
    __syncthreads();
  }

  const int rbase = m0 + wm * 32 + (lane >> 4) * 4;  // + i*16 + reg
  const int cbase = n0 + wn * 32 + fr;               // + j*16
  if (z < 2) {
    float* __restrict__ O = (z == 0) ? A : Bm;
#pragma unroll
    for (int i = 0; i < 2; ++i)
#pragma unroll
      for (int j = 0; j < 2; ++j)
#pragma unroll
        for (int r = 0; r < 4; ++r)
          O[(size_t)(rbase + i * 16 + r) * DD + cbase + j * 16] = acc[i][j][r];
  } else {
#pragma unroll
    for (int i = 0; i < 2; ++i)
#pragma unroll
      for (int j = 0; j < 2; ++j) {
        int row = rbase + i * 16;       // global token index 0..2047
        int bb = row >> 8, jj = row & 255;
        int c = cbase + j * 16;
        ushort4 pk;
        pk.x = f2bf(acc[i][j][0]); pk.y = f2bf(acc[i][j][1]);
        pk.z = f2bf(acc[i][j][2]); pk.w = f2bf(acc[i][j][3]);
        *(ushort4*)&Hjt[((size_t)(bb * 256 + c)) * 256 + jj] = pk;
      }
  }
}

// ---------------------------------------------------------------------------
// Kernel 2: edge scores t[b,i,j] = sum_c w2_c * relu(A_ic + B_jc).
// ZERO LDS: A rows + w2 live in registers; B rows stream from L2 with 8-way
// lane broadcast; c-group reduction via shfl_xor (VALU pipe). Raw t written
// (masking deferred to softmax). Grid (8 jt, 8 it, 8 b) = 512 blocks.
// ---------------------------------------------------------------------------
__global__ __launch_bounds__(256) void edge_kernel(
    const float* __restrict__ A, const float* __restrict__ Bm,
    const float* __restrict__ w2, float* __restrict__ T) {
  const int jt = blockIdx.x, it = blockIdx.y, b = blockIdx.z;
  const int tid = threadIdx.x;
  const int w = tid >> 6, l = tid & 63;
  const int cg = l & 7;    // c-group: c in [cg*32, cg*32+32)
  const int ip = l >> 3;   // i-pair within wave's 16 rows
  const int i0 = it * 32 + (w >> 1) * 16;
  const int j0 = jt * 32 + (w & 1) * 16;

  const float* __restrict__ Ar0 = A + ((size_t)(b * LL + i0 + ip * 2)) * DD + cg * 32;
  const float* __restrict__ Ar1 = Ar0 + DD;
  const float* __restrict__ Bb = Bm + ((size_t)(b * LL + j0)) * DD + cg * 32;

  float a0[32], a1[32], wv[32];
#pragma unroll
  for (int ch = 0; ch < 8; ++ch) {
    *(float4*)&a0[ch * 4] = *(const float4*)&Ar0[ch * 4];
    *(float4*)&a1[ch * 4] = *(const float4*)&Ar1[ch * 4];
    *(float4*)&wv[ch * 4] = *(const float4*)&w2[cg * 32 + ch * 4];
  }

  float o00 = 0.f, o01 = 0.f, o10 = 0.f, o11 = 0.f;
#pragma unroll 4
  for (int j = 0; j < 16; ++j) {
    float p0 = 0.f, p1 = 0.f;
#pragma unroll
    for (int ch = 0; ch < 8; ++ch) {
      float bv[4];
      *(float4*)&bv[0] = *(const float4*)&Bb[(size_t)j * DD + ch * 4];
#pragma unroll
      for (int u = 0; u < 4; ++u) {
        float bb = bv[u], ww = wv[ch * 4 + u];
        p0 = fmaf(ww, fmaxf(a0[ch * 4 + u] + bb, 0.f), p0);
        p1 = fmaf(ww, fmaxf(a1[ch * 4 + u] + bb, 0.f), p1);
      }
    }
    // reduce across the 8 c-groups (lanes xor 1,2,4)
    p0 += __shfl_xor(p0, 1); p1 += __shfl_xor(p1, 1);
    p0 += __shfl_xor(p0, 2); p1 += __shfl_xor(p1, 2);
    p0 += __shfl_xor(p0, 4); p1 += __shfl_xor(p1, 4);
    bool own = (cg == (j >> 1));
    if (j & 1) { o01 = own ? p0 : o01; o11 = own ? p1 : o11; }
    else       { o00 = own ? p0 : o00; o10 = own ? p1 : o10; }
  }
  float* Tr = T + ((size_t)(b * LL + i0 + ip * 2)) * LL + j0 + cg * 2;
  *(float2*)Tr = make_float2(o00, o01);
  *(float2*)(Tr + LL) = make_float2(o10, o11);
}

// ---------------------------------------------------------------------------
// Kernel 3: masked softmax over j (mask from sdep), output w in bf16.
// One wave per row, 4 rows per block, 512 blocks.
// ---------------------------------------------------------------------------
__global__ __launch_bounds__(256) void softmax_kernel(
    const float* __restrict__ T, const int* __restrict__ sdep,
    ushort* __restrict__ wb) {
  const int row = blockIdx.x * 4 + (threadIdx.x >> 6);
  const int l = threadIdx.x & 63;
  const float* __restrict__ tr = T + (size_t)row * LL;
  const int* __restrict__ sr = sdep + (size_t)row * LL;
  float v[4];
  float m = -3.0e38f;
#pragma unroll
  for (int k = 0; k < 4; ++k) {
    bool e = sr[l + 64 * k] > 0;
    v[k] = e ? tr[l + 64 * k] : -3.0e38f;
    m = fmaxf(m, v[k]);
  }
#pragma unroll
  for (int off = 32; off >= 1; off >>= 1) m = fmaxf(m, __shfl_xor(m, off));
  float s = 0.f;
#pragma unroll
  for (int k = 0; k < 4; ++k) {
    float e = (v[k] > -1.0e30f) ? __expf(v[k] - m) : 0.f;
    v[k] = e;
    s += e;
  }
#pragma unroll
  for (int off = 32; off >= 1; off >>= 1) s += __shfl_xor(s, off);
  float inv = (s > 0.f) ? 1.0f / s : 0.f;
#pragma unroll
  for (int k = 0; k < 4; ++k) wb[(size_t)row * LL + l + 64 * k] = f2bf(v[k] * inv);
}

// ---------------------------------------------------------------------------
// Kernel 4: agg via MFMA: agg[b,i,c] = sum_j w[b,i,j] * Hj[b,j,c];
// out = relu(Q + agg). A-frag = wb rows (contiguous j), B-frag = Hjt rows
// (contiguous j). Tile 64i x 32c, grid (8 ct, 4 it, 8 b) = 256 blocks.
// ---------------------------------------------------------------------------
__global__ __launch_bounds__(256) void agg_mfma(
    const float* __restrict__ Q, const ushort* __restrict__ wb,
    const ushort* __restrict__ Hjt, float* __restrict__ out) {
  const int ct = blockIdx.x, it = blockIdx.y, b = blockIdx.z;
  __shared__ __align__(16) ushort WS[64][32];  // w tile [i][j-chunk]
  __shared__ __align__(16) ushort HS[32][32];  // Hjt tile [c][j-chunk]
  const int tid = threadIdx.x;
  const int i0 = it * 64, c0 = ct * 32;
  const int w = tid >> 6, lane = tid & 63;
  const int fr = lane & 15, fk = (lane >> 4) * 8;

  f32x4 acc[2] = {};
  for (int j0 = 0; j0 < LL; j0 += 32) {
    {
      int r = tid >> 2, kc = (tid & 3) * 8;
      *(uint4*)&WS[r][kc] = *(const uint4*)&wb[((size_t)(b * LL + i0 + r)) * LL + j0 + kc];
    }
    if (tid < 128) {
      int r = tid >> 2, kc = (tid & 3) * 8;
      *(uint4*)&HS[r][kc] = *(const uint4*)&Hjt[((size_t)(b * 256 + c0 + r)) * 256 + j0 + kc];
    }
    __syncthreads();
    short8v a = *(const short8v*)&WS[w * 16 + fr][fk];
    short8v b0 = *(const short8v*)&HS[fr][fk];
    short8v b1 = *(const short8v*)&HS[16 + fr][fk];
    acc[0] = __builtin_amdgcn_mfma_f32_16x16x32_bf16(a, b0, acc[0], 0, 0, 0);
    acc[1] = __builtin_amdgcn_mfma_f32_16x16x32_bf16(a, b1, acc[1], 0, 0, 0);
    __syncthreads();
  }

  const int ibase = i0 + w * 16 + (lane >> 4) * 4;
#pragma unroll
  for (int jf = 0; jf < 2; ++jf)
#pragma unroll
    for (int r = 0; r < 4; ++r) {
      int i = ibase + r, c = c0 + jf * 16 + fr;
      size_t off = ((size_t)(b * LL + i)) * DD + c;
      out[off] = fmaxf(Q[off] + acc[jf][r], 0.f);
    }
}

extern "C" void kernel_launch(void* const* d_in, const int* in_sizes, int n_in,
                              void* d_out, int out_size, void* d_ws, size_t ws_size,
                              hipStream_t stream) {
  const float* Q    = (const float*)d_in[0];
  const int*   wl   = (const int*)d_in[1];
  const int*   sdep = (const int*)d_in[2];
  const float* Wa   = (const float*)d_in[3];
  const float* Wb   = (const float*)d_in[4];
  const float* w2   = (const float*)d_in[5];
  const float* Wd   = (const float*)d_in[6];
  float* out = (float*)d_out;
  float* ws  = (float*)d_ws;

  float* A  = ws;                  // [2048][256] fp32
  float* Bm = ws + 524288;         // [2048][256] fp32
  float* T  = ws + 1048576;        // [2048][256] fp32 raw edge scores
  ushort* bf  = (ushort*)(ws + 1572864);
  ushort* Qb  = bf;                // [2048][256] bf16
  ushort* Wab = Qb + 524288;       // [256][256] bf16
  ushort* Wbb = Wab + 65536;
  ushort* Wdb = Wbb + 65536;
  ushort* Hjt = Wdb + 65536;       // [8][256 c][256 j] bf16 (transposed Hj)
  ushort* wbv = Hjt + 524288;      // [2048][256] bf16 softmax weights

  prep_kernel<<<1218, 256, 0, stream>>>(Q, Wa, Wb, Wd, wl, sdep,
                                        Qb, Wab, Wbb, Wdb, out + 524288);
  gemm3_mfma<<<dim3(32, 4, 3), 256, 0, stream>>>(Qb, Wab, Wbb, Wdb, A, Bm, Hjt);
  edge_kernel<<<dim3(8, 8, 8), 256, 0, stream>>>(A, Bm, w2, T);
  softmax_kernel<<<512, 256, 0, stream>>>(T, sdep, wbv);
  agg_mfma<<<dim3(8, 4, 8), 256, 0, stream>>>(Q, wbv, Hjt, out);
}